// Round 6
// baseline (280.745 us; speedup 1.0000x reference)
//
#include <hip/hip_runtime.h>

// B=8, N=1024, C=1024, H=16, HD=64
// R19 (= R18 resubmit; container-level failure last round, kernel re-audited:
//      vmcnt FIFO accounting, barrier uniformity, WAR hazards, LDS bounds,
//      swizzle algebra all verified statically).
//      256² 4-phase template, phases = (m-half h, K-half κ); stage units
//      aligned to consumption: A by h-rows, B by κ ([2][κ][256][32], 2-way
//      free swizzle). Issue: P1(t)->Ah1,Bκ1(t+1); P3(t)->Ah0(t+2);
//      P4(t)->Bκ0(t+2): every unit lands 5-6 phases before first read.
//      vmcnt(8) at ends of P1/P4 only; raw s_barrier; setprio on MFMA.
//      Attention (R9) and convert unchanged.

typedef __attribute__((ext_vector_type(8))) short bf16x8;
typedef __attribute__((ext_vector_type(4))) short bf16x4;
typedef __attribute__((ext_vector_type(4))) float f32x4;

__device__ __forceinline__ short f2bf(float f) {
    union { float f; unsigned u; } x;
    x.f = f;
    unsigned r = x.u + 0x7fffu + ((x.u >> 16) & 1u);  // RNE
    return (short)(r >> 16);
}

__device__ __forceinline__ void load_lds16(const void* g, void* l) {
    __builtin_amdgcn_global_load_lds((const __attribute__((address_space(1))) unsigned*)g,
                                     (__attribute__((address_space(3))) unsigned*)l,
                                     16, 0, 0);
}

// ---------------- merged fp32 -> bf16 convert ----------------
__global__ __launch_bounds__(256) void convert_all(const float* __restrict__ x,
                                                   const float* __restrict__ wqkv,
                                                   const float* __restrict__ wproj,
                                                   short* __restrict__ xb,
                                                   short* __restrict__ wqkvb,
                                                   short* __restrict__ wprojb) {
    int i = blockIdx.x * 256 + threadIdx.x;
    const float* src;
    short* dst;
    int j;
    if (i < 2097152)      { src = x;     dst = xb;     j = i; }
    else if (i < 2883584) { src = wqkv;  dst = wqkvb;  j = i - 2097152; }
    else                  { src = wproj; dst = wprojb; j = i - 2883584; }
    float4 v = *(const float4*)(src + j * 4);
    unsigned lo = (unsigned short)f2bf(v.x) | ((unsigned)(unsigned short)f2bf(v.y) << 16);
    unsigned hi = (unsigned short)f2bf(v.z) | ((unsigned)(unsigned short)f2bf(v.w) << 16);
    uint2 p; p.x = lo; p.y = hi;
    *(uint2*)(dst + j * 4) = p;
}

// ---------------- 256x256 4-phase GEMM (consumption-aligned staging) ----------------
// 8 waves 2Mx4N (wave 128x64), BK=64, dbuf. LDS: A[2][256][64] + B[2][2][256][32].
// EPI=0: QKV scatter epilogue. EPI=1: proj f32+bias epilogue.
template<int EPI, int NTX>
__global__ __launch_bounds__(512, 2) void gemmkp(const short* __restrict__ A,
                                                 const short* __restrict__ Bt,
                                                 short* __restrict__ q,
                                                 short* __restrict__ kk,
                                                 short* __restrict__ vt,
                                                 const float* __restrict__ bias,
                                                 float* __restrict__ out) {
    extern __shared__ short lds[];
    short* const As = lds;            // [2][256][64]
    short* const Bs = lds + 32768;    // [2][2][256][32]
    const int K = 1024;
    constexpr int NWG = 32 * NTX;
    constexpr int CHUNK = NWG / 8;

    const int bid = blockIdx.x;
    const int tile = (bid & 7) * CHUNK + (bid >> 3);   // XCD-bijective (NWG%8==0)
    const int m0 = (tile / NTX) * 256;
    const int n0 = (tile % NTX) * 256;

    const int t = threadIdx.x;
    const int w = t >> 6, lane = t & 63, quad = lane >> 4, l16 = lane & 15;
    const int wm = (w >> 2) * 128, wn = (w & 3) * 64;
    const int swA = l16 & 7, swB = (l16 >> 1) & 3;

    // A staging: lane row = t>>3 (64-row chunks), 8 slots of 16B, XOR row&7
    const int srA = t >> 3;
    const int scA = ((t & 7) ^ (srA & 7)) * 8;
    // B staging: lane row = t>>2 (128-row chunks), 4 slots of 16B, XOR (row>>1)&3
    const int srB = t >> 2;
    const int scB = ((t & 3) ^ ((srB >> 1) & 3)) * 8;

    const short* Ag = A  + (m0 + srA) * K + scA;
    const short* Bg = Bt + (n0 + srB) * K + scB;

    f32x4 acc[8][4];
    #pragma unroll
    for (int mi = 0; mi < 8; ++mi)
        #pragma unroll
        for (int ni = 0; ni < 4; ++ni) acc[mi][ni] = (f32x4){0.f, 0.f, 0.f, 0.f};

    bf16x8 af[4], bf[4];

    // unit Ah(h): rows {h*64..h*64+63, h*64+128..h*64+191} (2 loads)
#define STG_A(kt_, h_) do { \
    load_lds16(Ag + ((h_) * 64) * 1024 + (kt_) * 64, \
               As + ((kt_) & 1) * 16384 + ((h_) * 64 + w * 8) * 64); \
    load_lds16(Ag + ((h_) * 64 + 128) * 1024 + (kt_) * 64, \
               As + ((kt_) & 1) * 16384 + ((h_) * 64 + 128 + w * 8) * 64); } while (0)
    // unit Bk(kap): all 256 rows, K-half kap (2 loads)
#define STG_B(kt_, kap_) do { \
    load_lds16(Bg + (kt_) * 64 + (kap_) * 32, \
               Bs + ((kt_) & 1) * 16384 + (kap_) * 8192 + (w * 16) * 32); \
    load_lds16(Bg + 128 * 1024 + (kt_) * 64 + (kap_) * 32, \
               Bs + ((kt_) & 1) * 16384 + (kap_) * 8192 + (128 + w * 16) * 32); } while (0)

#define READ_FRAGS(h_, kap_) do { \
    _Pragma("unroll") \
    for (int mi = 0; mi < 4; ++mi) \
        af[mi] = *(const bf16x8*)(Ar + (wm + (h_) * 64 + mi * 16 + l16) * 64 + (((kap_) * 4 + quad) ^ swA) * 8); \
    _Pragma("unroll") \
    for (int ni = 0; ni < 4; ++ni) \
        bf[ni] = *(const bf16x8*)(Br + (kap_) * 8192 + (wn + ni * 16 + l16) * 32 + (quad ^ swB) * 8); } while (0)

#define MFMA16(h_) do { \
    __builtin_amdgcn_s_setprio(1); \
    _Pragma("unroll") \
    for (int mi = 0; mi < 4; ++mi) \
        _Pragma("unroll") \
        for (int ni = 0; ni < 4; ++ni) \
            acc[(h_) * 4 + mi][ni] = __builtin_amdgcn_mfma_f32_16x16x32_bf16(af[mi], bf[ni], acc[(h_) * 4 + mi][ni], 0, 0, 0); \
    __builtin_amdgcn_s_setprio(0); } while (0)

#define BAR   asm volatile("s_barrier" ::: "memory")
#define LGKM0 asm volatile("s_waitcnt lgkmcnt(0)" ::: "memory")
#define VM(n) asm volatile("s_waitcnt vmcnt(" #n ")" ::: "memory")

    // prologue: t0 fully + t1's {Ah0,Bk0}; oldest-4 landed -> P1(0) ready
    STG_A(0, 0); STG_B(0, 0); STG_A(0, 1); STG_B(0, 1);
    STG_A(1, 0); STG_B(1, 0);
    VM(8);
    BAR;

    #pragma unroll 1
    for (int kt = 0; kt < 16; ++kt) {
        const short* Ar = As + (kt & 1) * 16384;
        const short* Br = Bs + (kt & 1) * 16384;

        // ---- P1 (h0,k0); stage Ah1,Bk1 of kt+1 ----
        READ_FRAGS(0, 0);
        if (kt < 15) { STG_A(kt + 1, 1); STG_B(kt + 1, 1); }
        BAR; LGKM0;
        MFMA16(0);
        if (kt < 15) VM(8); else VM(0);
        BAR;

        // ---- P2 (h0,k1) ----
        READ_FRAGS(0, 1);
        BAR; LGKM0;
        MFMA16(0);
        BAR;

        // ---- P3 (h1,k0); stage Ah0 of kt+2 (its rows' readers retired) ----
        READ_FRAGS(1, 0);
        if (kt < 14) STG_A(kt + 2, 0);
        BAR; LGKM0;
        MFMA16(1);
        BAR;

        // ---- P4 (h1,k1); stage Bk0 of kt+2 ----
        READ_FRAGS(1, 1);
        if (kt < 14) STG_B(kt + 2, 0);
        BAR; LGKM0;
        MFMA16(1);
        if (kt < 14) VM(8); else if (kt == 14) VM(4);
        BAR;
    }
#undef STG_A
#undef STG_B
#undef READ_FRAGS
#undef MFMA16
#undef BAR
#undef LGKM0
#undef VM

    // ---- epilogue ----
    if (EPI == 0) {
        const float QS = 0.125f * 1.44269504088896f;
        #pragma unroll
        for (int ni = 0; ni < 4; ++ni) {
            int col = n0 + wn + ni * 16 + l16;
            int sect = col >> 10;
            int c = col & 1023;
            int h = c >> 6, dd = c & 63;
            #pragma unroll
            for (int mi = 0; mi < 8; ++mi) {
                #pragma unroll
                for (int r = 0; r < 4; ++r) {
                    int m = m0 + wm + mi * 16 + quad * 4 + r;
                    int b = m >> 10, i = m & 1023;
                    float v = acc[mi][ni][r];
                    if (sect == 0)      q[((b * 16 + h) * 1024 + i) * 64 + dd] = f2bf(v * QS);
                    else if (sect == 1) kk[((b * 16 + h) * 1024 + i) * 64 + dd] = f2bf(v);
                    else                vt[((b * 16 + h) * 64 + dd) * 1024 + i] = f2bf(v);
                }
            }
        }
    } else {
        #pragma unroll
        for (int ni = 0; ni < 4; ++ni) {
            int col = n0 + wn + ni * 16 + l16;
            float bv = bias[col];
            #pragma unroll
            for (int mi = 0; mi < 8; ++mi) {
                #pragma unroll
                for (int r = 0; r < 4; ++r) {
                    int m = m0 + wm + mi * 16 + quad * 4 + r;
                    out[m * 1024 + col] = acc[mi][ni][r] + bv;
                }
            }
        }
    }
}

// ---------------- Flash attention: dbuf K/V, 1 barrier/jt, register P (R9) ----------------
__global__ __launch_bounds__(256) void attn_kernel(const short* __restrict__ q,
                                                   const short* __restrict__ k,
                                                   const short* __restrict__ vt,
                                                   short* __restrict__ ao) {
    __shared__ alignas(16) short Ks[2][64][72];
    __shared__ alignas(16) short Vs[2][64][72];

    const int bh = blockIdx.y, qt = blockIdx.x;
    const int t = threadIdx.x, w = t >> 6, lane = t & 63, quad = lane >> 4, l16 = lane & 15;
    const short* qg = q  + (bh * 1024 + qt * 128) * 64;
    const short* kg = k  + bh * 65536;
    const short* vg = vt + bh * 65536;

    bf16x8 qf[2][2];
    for (int mi = 0; mi < 2; ++mi) {
        const short* qr = qg + (w * 32 + mi * 16 + l16) * 64;
        qf[mi][0] = *(const bf16x8*)(qr + quad * 8);
        qf[mi][1] = *(const bf16x8*)(qr + 32 + quad * 8);
    }

    const int r0 = t >> 3,          c80 = (t & 7) * 8;
    const int r1 = (t + 256) >> 3,  c81 = c80;

    float rs[2] = {0.f, 0.f};
    f32x4 oaccT[2][4];
    for (int mi = 0; mi < 2; ++mi)
        for (int dt = 0; dt < 4; ++dt) oaccT[mi][dt] = (f32x4){0.f, 0.f, 0.f, 0.f};

    {
        float4 a = *(const float4*)&kg[r0 * 64 + c80];
        float4 b = *(const float4*)&kg[r1 * 64 + c81];
        float4 c = *(const float4*)&vg[r0 * 1024 + c80];
        float4 d = *(const float4*)&vg[r1 * 1024 + c81];
        *(float4*)&Ks[0][r0][c80] = a;  *(float4*)&Ks[0][r1][c81] = b;
        *(float4*)&Vs[0][r0][c80] = c;  *(float4*)&Vs[0][r1][c81] = d;
    }

    for (int jt = 0; jt < 16; ++jt) {
        const int cur = jt & 1;
        asm volatile("s_waitcnt lgkmcnt(0)" ::: "memory");
        asm volatile("s_barrier" ::: "memory");

        float4 kr0, kr1, vr0, vr1;
        if (jt < 15) {
            int jn = jt + 1;
            kr0 = *(const float4*)&kg[(jn * 64 + r0) * 64 + c80];
            kr1 = *(const float4*)&kg[(jn * 64 + r1) * 64 + c81];
            vr0 = *(const float4*)&vg[r0 * 1024 + jn * 64 + c80];
            vr1 = *(const float4*)&vg[r1 * 1024 + jn * 64 + c81];
        }

        for (int js = 0; js < 4; ++js) {
            bf16x8 kf0 = *(const bf16x8*)&Ks[cur][js * 16 + l16][quad * 8];
            bf16x8 kf1 = *(const bf16x8*)&Ks[cur][js * 16 + l16][32 + quad * 8];
            bf16x4 vtf[4];
            for (int dt = 0; dt < 4; ++dt)
                vtf[dt] = *(const bf16x4*)&Vs[cur][dt * 16 + l16][js * 16 + quad * 4];
            for (int mi = 0; mi < 2; ++mi) {
                f32x4 s = (f32x4){0.f, 0.f, 0.f, 0.f};
                s = __builtin_amdgcn_mfma_f32_16x16x32_bf16(kf0, qf[mi][0], s, 0, 0, 0);
                s = __builtin_amdgcn_mfma_f32_16x16x32_bf16(kf1, qf[mi][1], s, 0, 0, 0);
                bf16x4 pfrag;
                for (int r = 0; r < 4; ++r) {
                    float p = __builtin_amdgcn_exp2f(s[r]);
                    rs[mi] += p;
                    pfrag[r] = f2bf(p);
                }
                for (int dt = 0; dt < 4; ++dt)
                    oaccT[mi][dt] = __builtin_amdgcn_mfma_f32_16x16x16bf16_1k(
                        vtf[dt], pfrag, oaccT[mi][dt], 0, 0, 0);
            }
        }

        if (jt < 15) {
            const int nxt = cur ^ 1;
            *(float4*)&Ks[nxt][r0][c80] = kr0;  *(float4*)&Ks[nxt][r1][c81] = kr1;
            *(float4*)&Vs[nxt][r0][c80] = vr0;  *(float4*)&Vs[nxt][r1][c81] = vr1;
        }
    }

    for (int mi = 0; mi < 2; ++mi) {
        rs[mi] += __shfl_xor(rs[mi], 16, 64);
        rs[mi] += __shfl_xor(rs[mi], 32, 64);
    }

    const int b = bh >> 4, h = bh & 15;
    for (int mi = 0; mi < 2; ++mi) {
        float inv = 1.0f / rs[mi];
        int i = qt * 128 + w * 32 + mi * 16 + l16;
        short* aor = ao + (b * 1024 + i) * 1024 + h * 64;
        for (int dt = 0; dt < 4; ++dt) {
            bf16x4 o4;
            for (int r = 0; r < 4; ++r) o4[r] = f2bf(oaccT[mi][dt][r] * inv);
            *(bf16x4*)(aor + dt * 16 + quad * 4) = o4;
        }
    }
}

extern "C" void kernel_launch(void* const* d_in, const int* in_sizes, int n_in,
                              void* d_out, int out_size, void* d_ws, size_t ws_size,
                              hipStream_t stream) {
    const float* x      = (const float*)d_in[0];
    const float* w_qkv  = (const float*)d_in[1];
    const float* w_proj = (const float*)d_in[2];
    const float* b_proj = (const float*)d_in[3];
    float* out = (float*)d_out;

    char* ws = (char*)d_ws;
    short* xb     = (short*)(ws);
    short* wqkvb  = (short*)(ws + 16777216);
    short* wprojb = (short*)(ws + 23068672);
    short* qb     = (short*)(ws + 25165824);
    short* kb     = (short*)(ws + 41943040);
    short* vtb    = (short*)(ws + 58720256);
    short* aob    = (short*)(ws + 75497472);

    static bool s_init = false;
    if (!s_init) {
        hipFuncSetAttribute(reinterpret_cast<const void*>(&gemmkp<0, 12>),
                            hipFuncAttributeMaxDynamicSharedMemorySize, 131072);
        hipFuncSetAttribute(reinterpret_cast<const void*>(&gemmkp<1, 4>),
                            hipFuncAttributeMaxDynamicSharedMemorySize, 131072);
        s_init = true;
    }

    convert_all<<<12288, 256, 0, stream>>>(x, w_qkv, w_proj, xb, wqkvb, wprojb);
    // QKV: M=8192,N=3072 -> 32x12 tiles of 256x256 = 384 blocks
    gemmkp<0, 12><<<384, 512, 131072, stream>>>(xb, wqkvb, qb, kb, vtb, nullptr, nullptr);
    attn_kernel<<<dim3(8, 128), 256, 0, stream>>>(qb, kb, vtb, aob);
    // proj: M=8192,N=1024 -> 32x4 tiles of 256x256 = 128 blocks
    gemmkp<1, 4><<<128, 512, 131072, stream>>>(aob, wprojb, nullptr, nullptr, nullptr, b_proj, out);
}

// Round 7
// 254.185 us; speedup vs baseline: 1.1045x; 1.1045x over previous
//
#include <hip/hip_runtime.h>

// B=8, N=1024, C=1024, H=16, HD=64
// R20: R17 (best GEMM so far, 86us QKV) + the T3 "minimum 2-phase" recipe:
//      double-buffered LDS (64KB dyn), dist-1 prefetch issued BEFORE the
//      compute phase, ONE __syncthreads per K-tile (compiler emits the
//      vmcnt/lgkm drain). No manual asm waits anywhere (R14-R19 lesson:
//      every hand-asm schedule lost to compiler-managed sync).
//      128x128 tile, 4 waves, BK=64, __launch_bounds__(256,2) -> 2 blocks/CU.
//      Pre-swizzled-source staging + XOR read (0 conflicts), XCD-bijective
//      block swizzle, R13 epilogues retained. Attention (R9) and convert
//      unchanged.

typedef __attribute__((ext_vector_type(8))) short bf16x8;
typedef __attribute__((ext_vector_type(4))) short bf16x4;
typedef __attribute__((ext_vector_type(4))) float f32x4;

__device__ __forceinline__ short f2bf(float f) {
    union { float f; unsigned u; } x;
    x.f = f;
    unsigned r = x.u + 0x7fffu + ((x.u >> 16) & 1u);  // RNE
    return (short)(r >> 16);
}

__device__ __forceinline__ void load_lds16(const void* g, void* l) {
    __builtin_amdgcn_global_load_lds((const __attribute__((address_space(1))) unsigned*)g,
                                     (__attribute__((address_space(3))) unsigned*)l,
                                     16, 0, 0);
}

// ---------------- merged fp32 -> bf16 convert ----------------
__global__ __launch_bounds__(256) void convert_all(const float* __restrict__ x,
                                                   const float* __restrict__ wqkv,
                                                   const float* __restrict__ wproj,
                                                   short* __restrict__ xb,
                                                   short* __restrict__ wqkvb,
                                                   short* __restrict__ wprojb) {
    int i = blockIdx.x * 256 + threadIdx.x;
    const float* src;
    short* dst;
    int j;
    if (i < 2097152)      { src = x;     dst = xb;     j = i; }
    else if (i < 2883584) { src = wqkv;  dst = wqkvb;  j = i - 2097152; }
    else                  { src = wproj; dst = wprojb; j = i - 2883584; }
    float4 v = *(const float4*)(src + j * 4);
    unsigned lo = (unsigned short)f2bf(v.x) | ((unsigned)(unsigned short)f2bf(v.y) << 16);
    unsigned hi = (unsigned short)f2bf(v.z) | ((unsigned)(unsigned short)f2bf(v.w) << 16);
    uint2 p; p.x = lo; p.y = hi;
    *(uint2*)(dst + j * 4) = p;
}

// ---------------- 128x128 GEMM, dbuf dist-1, single barrier/K-tile ----------------
// 4 waves (2x2 of 64x64), BK=64. LDS: A[2][128][64] + B[2][128][64] = 64KB dyn.
// Loop: { STAGE(kt+1 -> buf^1); ds_read buf; MFMA; __syncthreads }.
// EPI=0: QKV scatter epilogue. EPI=1: proj f32+bias epilogue.
template<int EPI, int NTX>
__global__ __launch_bounds__(256, 2) void gemmdb(const short* __restrict__ A,
                                                 const short* __restrict__ Bt,
                                                 short* __restrict__ q,
                                                 short* __restrict__ kk,
                                                 short* __restrict__ vt,
                                                 const float* __restrict__ bias,
                                                 float* __restrict__ out) {
    extern __shared__ short lds[];          // A[2][128][64] | B[2][128][64]
    const int K = 1024;
    constexpr int NWG = 64 * NTX;           // (8192/128) * NTX
    constexpr int CHUNK = NWG / 8;

    const int bid = blockIdx.x;
    const int tile = (bid & 7) * CHUNK + (bid >> 3);   // XCD-bijective (NWG%8==0)
    const int m0 = (tile / NTX) * 128;
    const int n0 = (tile % NTX) * 128;

    const int t = threadIdx.x;
    const int w = t >> 6, lane = t & 63, quad = lane >> 4, l16 = lane & 15;
    const int wm = (w >> 1) * 64, wn = (w & 1) * 64;
    const int sw = l16 & 7;

    // staging: round r covers rows r*32 + srow; source col pre-swizzled so the
    // linear global_load_lds dest yields LDS[row][slot] = G[row][slot ^ (row&7)]
    const int srow = t >> 3;                            // 0..31
    const int scol = ((t & 7) ^ (srow & 7)) * 8;
    const short* Ag = A  + (m0 + srow) * K + scol;
    const short* Bg = Bt + (n0 + srow) * K + scol;
    const int w8 = w * 8 * 64;                          // wave-uniform dest slice

    f32x4 acc[4][4];
    #pragma unroll
    for (int mi = 0; mi < 4; ++mi)
        #pragma unroll
        for (int ni = 0; ni < 4; ++ni) acc[mi][ni] = (f32x4){0.f, 0.f, 0.f, 0.f};

    // stage full tile kt into buffer d (8 gloads: 4 A + 4 B)
#define STG(kt_, d_) do { \
    _Pragma("unroll") \
    for (int r = 0; r < 4; ++r) \
        load_lds16(Ag + r * 32 * K + (kt_) * 64, lds + (d_) * 8192 + r * 32 * 64 + w8); \
    _Pragma("unroll") \
    for (int r = 0; r < 4; ++r) \
        load_lds16(Bg + r * 32 * K + (kt_) * 64, lds + 16384 + (d_) * 8192 + r * 32 * 64 + w8); } while (0)

    // prologue: tile 0 -> buf 0; single drain barrier
    STG(0, 0);
    __syncthreads();

    #pragma unroll 1
    for (int kt = 0; kt < 16; ++kt) {
        const int d = kt & 1;
        if (kt < 15) STG(kt + 1, d ^ 1);    // dist-1 prefetch, in flight all phase

        const short* Ar = lds + d * 8192;
        const short* Br = lds + 16384 + d * 8192;
        bf16x8 af[4][2], bf[4][2];
        #pragma unroll
        for (int mi = 0; mi < 4; ++mi)
            #pragma unroll
            for (int c = 0; c < 2; ++c)
                af[mi][c] = *(const bf16x8*)(Ar + (wm + mi * 16 + l16) * 64 + (((quad + 4 * c) ^ sw) * 8));
        #pragma unroll
        for (int ni = 0; ni < 4; ++ni)
            #pragma unroll
            for (int c = 0; c < 2; ++c)
                bf[ni][c] = *(const bf16x8*)(Br + (wn + ni * 16 + l16) * 64 + (((quad + 4 * c) ^ sw) * 8));
        #pragma unroll
        for (int mi = 0; mi < 4; ++mi)
            #pragma unroll
            for (int ni = 0; ni < 4; ++ni) {
                acc[mi][ni] = __builtin_amdgcn_mfma_f32_16x16x32_bf16(af[mi][0], bf[ni][0], acc[mi][ni], 0, 0, 0);
                acc[mi][ni] = __builtin_amdgcn_mfma_f32_16x16x32_bf16(af[mi][1], bf[ni][1], acc[mi][ni], 0, 0, 0);
            }
        if (kt < 15) __syncthreads();       // drains prefetch; next buf readable
    }
#undef STG

    // ---- epilogue ----
    if (EPI == 0) {
        const float QS = 0.125f * 1.44269504088896f;
        #pragma unroll
        for (int ni = 0; ni < 4; ++ni) {
            int col = n0 + wn + ni * 16 + l16;
            int sect = col >> 10;
            int c = col & 1023;
            int h = c >> 6, dd = c & 63;
            #pragma unroll
            for (int mi = 0; mi < 4; ++mi) {
                #pragma unroll
                for (int r = 0; r < 4; ++r) {
                    int m = m0 + wm + mi * 16 + quad * 4 + r;
                    int b = m >> 10, i = m & 1023;
                    float v = acc[mi][ni][r];
                    if (sect == 0)      q[((b * 16 + h) * 1024 + i) * 64 + dd] = f2bf(v * QS);
                    else if (sect == 1) kk[((b * 16 + h) * 1024 + i) * 64 + dd] = f2bf(v);
                    else                vt[((b * 16 + h) * 64 + dd) * 1024 + i] = f2bf(v);
                }
            }
        }
    } else {
        #pragma unroll
        for (int ni = 0; ni < 4; ++ni) {
            int col = n0 + wn + ni * 16 + l16;
            float bv = bias[col];
            #pragma unroll
            for (int mi = 0; mi < 4; ++mi) {
                #pragma unroll
                for (int r = 0; r < 4; ++r) {
                    int m = m0 + wm + mi * 16 + quad * 4 + r;
                    out[m * 1024 + col] = acc[mi][ni][r] + bv;
                }
            }
        }
    }
}

// ---------------- Flash attention: dbuf K/V, 1 barrier/jt, register P (R9) ----------------
__global__ __launch_bounds__(256) void attn_kernel(const short* __restrict__ q,
                                                   const short* __restrict__ k,
                                                   const short* __restrict__ vt,
                                                   short* __restrict__ ao) {
    __shared__ alignas(16) short Ks[2][64][72];
    __shared__ alignas(16) short Vs[2][64][72];

    const int bh = blockIdx.y, qt = blockIdx.x;
    const int t = threadIdx.x, w = t >> 6, lane = t & 63, quad = lane >> 4, l16 = lane & 15;
    const short* qg = q  + (bh * 1024 + qt * 128) * 64;
    const short* kg = k  + bh * 65536;
    const short* vg = vt + bh * 65536;

    bf16x8 qf[2][2];
    for (int mi = 0; mi < 2; ++mi) {
        const short* qr = qg + (w * 32 + mi * 16 + l16) * 64;
        qf[mi][0] = *(const bf16x8*)(qr + quad * 8);
        qf[mi][1] = *(const bf16x8*)(qr + 32 + quad * 8);
    }

    const int r0 = t >> 3,          c80 = (t & 7) * 8;
    const int r1 = (t + 256) >> 3,  c81 = c80;

    float rs[2] = {0.f, 0.f};
    f32x4 oaccT[2][4];
    for (int mi = 0; mi < 2; ++mi)
        for (int dt = 0; dt < 4; ++dt) oaccT[mi][dt] = (f32x4){0.f, 0.f, 0.f, 0.f};

    {
        float4 a = *(const float4*)&kg[r0 * 64 + c80];
        float4 b = *(const float4*)&kg[r1 * 64 + c81];
        float4 c = *(const float4*)&vg[r0 * 1024 + c80];
        float4 d = *(const float4*)&vg[r1 * 1024 + c81];
        *(float4*)&Ks[0][r0][c80] = a;  *(float4*)&Ks[0][r1][c81] = b;
        *(float4*)&Vs[0][r0][c80] = c;  *(float4*)&Vs[0][r1][c81] = d;
    }

    for (int jt = 0; jt < 16; ++jt) {
        const int cur = jt & 1;
        asm volatile("s_waitcnt lgkmcnt(0)" ::: "memory");
        asm volatile("s_barrier" ::: "memory");

        float4 kr0, kr1, vr0, vr1;
        if (jt < 15) {
            int jn = jt + 1;
            kr0 = *(const float4*)&kg[(jn * 64 + r0) * 64 + c80];
            kr1 = *(const float4*)&kg[(jn * 64 + r1) * 64 + c81];
            vr0 = *(const float4*)&vg[r0 * 1024 + jn * 64 + c80];
            vr1 = *(const float4*)&vg[r1 * 1024 + jn * 64 + c81];
        }

        for (int js = 0; js < 4; ++js) {
            bf16x8 kf0 = *(const bf16x8*)&Ks[cur][js * 16 + l16][quad * 8];
            bf16x8 kf1 = *(const bf16x8*)&Ks[cur][js * 16 + l16][32 + quad * 8];
            bf16x4 vtf[4];
            for (int dt = 0; dt < 4; ++dt)
                vtf[dt] = *(const bf16x4*)&Vs[cur][dt * 16 + l16][js * 16 + quad * 4];
            for (int mi = 0; mi < 2; ++mi) {
                f32x4 s = (f32x4){0.f, 0.f, 0.f, 0.f};
                s = __builtin_amdgcn_mfma_f32_16x16x32_bf16(kf0, qf[mi][0], s, 0, 0, 0);
                s = __builtin_amdgcn_mfma_f32_16x16x32_bf16(kf1, qf[mi][1], s, 0, 0, 0);
                bf16x4 pfrag;
                for (int r = 0; r < 4; ++r) {
                    float p = __builtin_amdgcn_exp2f(s[r]);
                    rs[mi] += p;
                    pfrag[r] = f2bf(p);
                }
                for (int dt = 0; dt < 4; ++dt)
                    oaccT[mi][dt] = __builtin_amdgcn_mfma_f32_16x16x16bf16_1k(
                        vtf[dt], pfrag, oaccT[mi][dt], 0, 0, 0);
            }
        }

        if (jt < 15) {
            const int nxt = cur ^ 1;
            *(float4*)&Ks[nxt][r0][c80] = kr0;  *(float4*)&Ks[nxt][r1][c81] = kr1;
            *(float4*)&Vs[nxt][r0][c80] = vr0;  *(float4*)&Vs[nxt][r1][c81] = vr1;
        }
    }

    for (int mi = 0; mi < 2; ++mi) {
        rs[mi] += __shfl_xor(rs[mi], 16, 64);
        rs[mi] += __shfl_xor(rs[mi], 32, 64);
    }

    const int b = bh >> 4, h = bh & 15;
    for (int mi = 0; mi < 2; ++mi) {
        float inv = 1.0f / rs[mi];
        int i = qt * 128 + w * 32 + mi * 16 + l16;
        short* aor = ao + (b * 1024 + i) * 1024 + h * 64;
        for (int dt = 0; dt < 4; ++dt) {
            bf16x4 o4;
            for (int r = 0; r < 4; ++r) o4[r] = f2bf(oaccT[mi][dt][r] * inv);
            *(bf16x4*)(aor + dt * 16 + quad * 4) = o4;
        }
    }
}

extern "C" void kernel_launch(void* const* d_in, const int* in_sizes, int n_in,
                              void* d_out, int out_size, void* d_ws, size_t ws_size,
                              hipStream_t stream) {
    const float* x      = (const float*)d_in[0];
    const float* w_qkv  = (const float*)d_in[1];
    const float* w_proj = (const float*)d_in[2];
    const float* b_proj = (const float*)d_in[3];
    float* out = (float*)d_out;

    char* ws = (char*)d_ws;
    short* xb     = (short*)(ws);
    short* wqkvb  = (short*)(ws + 16777216);
    short* wprojb = (short*)(ws + 23068672);
    short* qb     = (short*)(ws + 25165824);
    short* kb     = (short*)(ws + 41943040);
    short* vtb    = (short*)(ws + 58720256);
    short* aob    = (short*)(ws + 75497472);

    static bool s_init = false;
    if (!s_init) {
        hipFuncSetAttribute(reinterpret_cast<const void*>(&gemmdb<0, 24>),
                            hipFuncAttributeMaxDynamicSharedMemorySize, 65536);
        hipFuncSetAttribute(reinterpret_cast<const void*>(&gemmdb<1, 8>),
                            hipFuncAttributeMaxDynamicSharedMemorySize, 65536);
        s_init = true;
    }

    convert_all<<<12288, 256, 0, stream>>>(x, w_qkv, w_proj, xb, wqkvb, wprojb);
    // QKV: M=8192,N=3072 -> 64x24 tiles of 128x128 = 1536 blocks (3 rounds @2/CU)
    gemmdb<0, 24><<<1536, 256, 65536, stream>>>(xb, wqkvb, qb, kb, vtb, nullptr, nullptr);
    attn_kernel<<<dim3(8, 128), 256, 0, stream>>>(qb, kb, vtb, aob);
    // proj: M=8192,N=1024 -> 64x8 tiles of 128x128 = 512 blocks (1 round @2/CU)
    gemmdb<1, 8><<<512, 256, 65536, stream>>>(aob, wprojb, nullptr, nullptr, nullptr, b_proj, out);
}